// Round 5
// baseline (1043.791 us; speedup 1.0000x reference)
//
#include <hip/hip_runtime.h>
#include <cstdint>
#include <cstddef>
#include <cmath>

#define B 4096
#define H 512
#define E 512
#define V 32000
#define NL 2
#define MAXLEN 99

typedef __attribute__((ext_vector_type(8))) short  bf16x8;
typedef __attribute__((ext_vector_type(4))) float  f32x4;
typedef __attribute__((ext_vector_type(8))) unsigned short ushort8;

__device__ __forceinline__ unsigned short f2b(float x) {
    union { float f; unsigned u; } c; c.f = x;
    unsigned r = c.u + 0x7fff + ((c.u >> 16) & 1);   // RNE to bf16
    return (unsigned short)(r >> 16);
}

#define GLOAD16(gp, lp)                                                        \
    __builtin_amdgcn_global_load_lds(                                          \
        (const __attribute__((address_space(1))) void*)(gp),                   \
        (__attribute__((address_space(3))) void*)(lp), 16, 0, 0)

// ---------------------------------------------------------------------------
// embed gather + build q = [emb, hidden0] and c2[:, :512] = emb
// ---------------------------------------------------------------------------
__global__ __launch_bounds__(256) void embed_concat_kernel(
    const int* __restrict__ tok, const float* __restrict__ emb,
    const float* __restrict__ hidden0, float* __restrict__ q, float* __restrict__ c2)
{
    const int b = blockIdx.x, t = threadIdx.x;
    const int v = tok[b];
    const float2 e = ((const float2*)(emb + (size_t)v * E))[t];
    ((float2*)(q  + (size_t)b * 1024))[t] = e;
    ((float2*)(c2 + (size_t)b * 1024))[t] = e;
    const float2 h = ((const float2*)(hidden0 + (size_t)b * H))[t];
    ((float2*)(q + (size_t)b * 1024 + 512))[t] = h;
}

// ---------------------------------------------------------------------------
// per-row attention: logits + softmax + weighted encoder sum
// ---------------------------------------------------------------------------
__global__ __launch_bounds__(256) void attn_fused_kernel(
    const float* __restrict__ q, const float* __restrict__ attn_W,
    const float* __restrict__ attn_b, const float* __restrict__ enc,
    float* __restrict__ attnw, float* __restrict__ c2)
{
    const int b = blockIdx.x, t = threadIdx.x;
    __shared__ float qs[1024];
    __shared__ float ls[128];

    ((float4*)qs)[t] = ((const float4*)(q + (size_t)b * 1024))[t];
    __syncthreads();

    float s = -1e30f;
    if (t < MAXLEN) {
        const float4* w4 = (const float4*)(attn_W + (size_t)t * 1024);
        const float4* q4 = (const float4*)qs;
        float ax = 0.f, ay = 0.f, az = 0.f, aw = 0.f;
        #pragma unroll 8
        for (int k = 0; k < 256; ++k) {
            const float4 a = q4[k], w = w4[k];
            ax += a.x * w.x; ay += a.y * w.y; az += a.z * w.z; aw += a.w * w.w;
        }
        s = (ax + ay) + (az + aw) + attn_b[t];
    }
    if (t < 128) ls[t] = s;
    __syncthreads();

    float mx = -1e30f;
    for (int i = 0; i < 128; ++i) mx = fmaxf(mx, ls[i]);
    __syncthreads();

    float ex = 0.f;
    if (t < MAXLEN) ex = expf(s - mx);
    if (t < 128) ls[t] = ex;
    __syncthreads();

    float sum = 0.f;
    for (int i = 0; i < 128; ++i) sum += ls[i];
    const float inv = 1.0f / sum;

    if (t < MAXLEN) attnw[(size_t)b * MAXLEN + t] = ex * inv;

    float accx = 0.f, accy = 0.f;
    const float2* encb = (const float2*)(enc + (size_t)b * MAXLEN * H);
    for (int l = 0; l < MAXLEN; ++l) {
        const float wl = ls[l];
        const float2 ev = encb[(size_t)l * 256 + t];
        accx += wl * ev.x; accy += wl * ev.y;
    }
    float2 outv; outv.x = accx * inv; outv.y = accy * inv;
    ((float2*)(c2 + (size_t)b * 1024 + 512))[t] = outv;
}

// ---------------------------------------------------------------------------
// fp32 -> bf16 conversion, 8 elems/thread, exact grid (n % 2048 == 0)
// ---------------------------------------------------------------------------
__global__ __launch_bounds__(256) void f32_to_bf16_kernel(
    const float* __restrict__ in, unsigned short* __restrict__ out)
{
    const size_t i = ((size_t)blockIdx.x * 256 + threadIdx.x) * 8;
    const float4 a = *(const float4*)(in + i);
    const float4 b = *(const float4*)(in + i + 4);
    ushort8 o;
    o[0] = f2b(a.x); o[1] = f2b(a.y); o[2] = f2b(a.z); o[3] = f2b(a.w);
    o[4] = f2b(b.x); o[5] = f2b(b.y); o[6] = f2b(b.z); o[7] = f2b(b.w);
    *(ushort8*)(out + i) = o;
}

// ---------------------------------------------------------------------------
// bf16 MFMA NT GEMM: C[m,n] = A[m,:] . W[n,:] + bias[n]
// BM=BN=128, BK=32, 256 thr (4 waves, 2x2 of 64x64), m97-class structure.
// SWZ: 1D grid, bijective XCD-chunked mapping (M fastest within an XCD slab).
// PARTIALS: epilogue emits per-(row, N-tile) softmax partials (max, sum-exp).
// ldc: output row stride in elements of the OUTPUT type (ushort if OUTBF).
// ---------------------------------------------------------------------------
template<int RELU, int OUTBF, int PARTIALS, int SWZ>
__global__ __launch_bounds__(256) void gemm_bf16_nt(
    const unsigned short* __restrict__ A, const unsigned short* __restrict__ Wb,
    const float* __restrict__ bias, void* __restrict__ Cv,
    int M, int N, int K, int ldc,
    float* __restrict__ pmax_g, float* __restrict__ psum_g)
{
    __shared__ __align__(16) unsigned short As[2][4096];   // [buf][128 rows][32 k]
    __shared__ __align__(16) unsigned short Bs[2][4096];

    const int tid  = threadIdx.x;
    int bn, bm;
    if (SWZ) {
        const int orig  = blockIdx.x;
        const int chunk = gridDim.x >> 3;          // blocks per XCD slab
        const int id    = (orig & 7) * chunk + (orig >> 3);
        const int mt    = M >> 7;
        bm = (id % mt) * 128;
        bn = (id / mt) * 128;
    } else {
        bn = blockIdx.x * 128;
        bm = blockIdx.y * 128;
    }
    const int lane = tid & 63;
    const int wid  = tid >> 6;
    const int wr   = (wid >> 1) * 64;      // wave row offset in tile
    const int wc   = (wid & 1) * 64;       // wave col offset in tile
    const int fr   = lane & 15;            // fragment row/col within 16
    const int fk   = (lane >> 4) * 8;      // k-elem offset (8 bf16 = 16B)

    f32x4 acc[4][4];
    #pragma unroll
    for (int m = 0; m < 4; ++m)
        #pragma unroll
        for (int n = 0; n < 4; ++n) acc[m][n] = (f32x4)0.f;

    const int srow = tid >> 2;             // 0..63
    const int sk   = (tid & 3) * 8;        // 0,8,16,24

    const unsigned short* ga = A  + (size_t)(bm + srow) * K + sk;
    const unsigned short* gb = Wb + (size_t)(bn + srow) * K + sk;

    // prologue: stage k0=0 into buf 0
    {
        GLOAD16(ga,                    &As[0][tid * 8]);
        GLOAD16(ga + (size_t)64 * K,   &As[0][2048 + tid * 8]);
        GLOAD16(gb,                    &Bs[0][tid * 8]);
        GLOAD16(gb + (size_t)64 * K,   &Bs[0][2048 + tid * 8]);
    }

    int buf = 0;
    for (int k0 = 0; k0 < K; k0 += 32) {
        __syncthreads();                   // staged loads for `buf` complete

        if (k0 + 32 < K) {                 // prefetch next into buf^1
            const int nb = buf ^ 1;
            GLOAD16(ga + k0 + 32,                  &As[nb][tid * 8]);
            GLOAD16(ga + k0 + 32 + (size_t)64 * K, &As[nb][2048 + tid * 8]);
            GLOAD16(gb + k0 + 32,                  &Bs[nb][tid * 8]);
            GLOAD16(gb + k0 + 32 + (size_t)64 * K, &Bs[nb][2048 + tid * 8]);
        }

        bf16x8 af[4], bf_[4];
        #pragma unroll
        for (int m = 0; m < 4; ++m)
            af[m] = *(const bf16x8*)&As[buf][(wr + m * 16 + fr) * 32 + fk];
        #pragma unroll
        for (int n = 0; n < 4; ++n)
            bf_[n] = *(const bf16x8*)&Bs[buf][(wc + n * 16 + fr) * 32 + fk];

        #pragma unroll
        for (int m = 0; m < 4; ++m)
            #pragma unroll
            for (int n = 0; n < 4; ++n)
                acc[m][n] = __builtin_amdgcn_mfma_f32_16x16x32_bf16(
                    af[m], bf_[n], acc[m][n], 0, 0, 0);

        buf ^= 1;
    }

    // per-lane bias for its 4 column fragments
    float bv[4];
    #pragma unroll
    for (int n = 0; n < 4; ++n) bv[n] = bias[bn + wc + n * 16 + fr];

    // epilogue stores: C/D layout col=lane&15, row=(lane>>4)*4+reg
    float* Cf = (float*)Cv;
    unsigned short* Cb = (unsigned short*)Cv;
    #pragma unroll
    for (int m = 0; m < 4; ++m) {
        #pragma unroll
        for (int n = 0; n < 4; ++n) {
            const int col = bn + wc + n * 16 + fr;
            const int row = bm + wr + m * 16 + (lane >> 4) * 4;
            #pragma unroll
            for (int r = 0; r < 4; ++r) {
                float v = acc[m][n][r] + bv[n];
                if (RELU) v = fmaxf(v, 0.f);
                if (OUTBF) Cb[(size_t)(row + r) * ldc + col] = f2b(v);
                else       Cf[(size_t)(row + r) * ldc + col] = v;
            }
        }
    }

    if constexpr (PARTIALS) {
        __shared__ float pm_s[2][2][64];
        __shared__ float ps_s[2][2][64];
        const int wrIdx = wid >> 1, wcIdx = wid & 1;

        #pragma unroll
        for (int m = 0; m < 4; ++m) {
            #pragma unroll
            for (int r = 0; r < 4; ++r) {
                float vmax = -1e30f;
                #pragma unroll
                for (int n = 0; n < 4; ++n) vmax = fmaxf(vmax, acc[m][n][r] + bv[n]);
                vmax = fmaxf(vmax, __shfl_xor(vmax, 1));
                vmax = fmaxf(vmax, __shfl_xor(vmax, 2));
                vmax = fmaxf(vmax, __shfl_xor(vmax, 4));
                vmax = fmaxf(vmax, __shfl_xor(vmax, 8));
                float vsum = 0.f;
                #pragma unroll
                for (int n = 0; n < 4; ++n) vsum += expf(acc[m][n][r] + bv[n] - vmax);
                vsum += __shfl_xor(vsum, 1);
                vsum += __shfl_xor(vsum, 2);
                vsum += __shfl_xor(vsum, 4);
                vsum += __shfl_xor(vsum, 8);
                const int rowh = m * 16 + (lane >> 4) * 4 + r;
                if (fr == 0) { pm_s[wrIdx][wcIdx][rowh] = vmax; ps_s[wrIdx][wcIdx][rowh] = vsum; }
            }
        }
        __syncthreads();
        if (wcIdx == 0) {
            const float m0 = pm_s[wrIdx][0][lane], m1 = pm_s[wrIdx][1][lane];
            const float s0 = ps_s[wrIdx][0][lane], s1 = ps_s[wrIdx][1][lane];
            const float Mx = fmaxf(m0, m1);
            const float S  = s0 * expf(m0 - Mx) + s1 * expf(m1 - Mx);
            const int row = bm + wr + lane;
            const int nt  = bn >> 7;
            const int NT  = N >> 7;
            pmax_g[(size_t)row * NT + nt] = Mx;
            psum_g[(size_t)row * NT + nt] = S;
        }
    }
}

// ---------------------------------------------------------------------------
// fp32 NT GEMM (fallback for logits if ws too small)
// ---------------------------------------------------------------------------
template<int RELU>
__global__ __launch_bounds__(256) void gemm_nt(
    const float* __restrict__ A, const float* __restrict__ W,
    const float* __restrict__ bias, float* __restrict__ C,
    int M, int N, int K)
{
    constexpr int BM = 128, BN = 128, BK = 32;
    __shared__ float As[BK][BM + 4];
    __shared__ float Bs[BK][BN + 4];

    const int tid = threadIdx.x;
    const int bn = blockIdx.x * BN;
    const int bm = blockIdx.y * BM;
    const int tx = tid & 15;
    const int ty = tid >> 4;

    float acc[8][8];
    #pragma unroll
    for (int i = 0; i < 8; ++i)
        #pragma unroll
        for (int j = 0; j < 8; ++j) acc[i][j] = 0.f;

    const int lkv = tid & 7;
    const int lm0 = tid >> 3;

    for (int k0 = 0; k0 < K; k0 += BK) {
        #pragma unroll
        for (int r = 0; r < 4; ++r) {
            const int m = lm0 + 32 * r;
            const float4 va = *(const float4*)(A + (size_t)(bm + m) * K + k0 + lkv * 4);
            As[lkv * 4 + 0][m] = va.x; As[lkv * 4 + 1][m] = va.y;
            As[lkv * 4 + 2][m] = va.z; As[lkv * 4 + 3][m] = va.w;
            const float4 vb = *(const float4*)(W + (size_t)(bn + m) * K + k0 + lkv * 4);
            Bs[lkv * 4 + 0][m] = vb.x; Bs[lkv * 4 + 1][m] = vb.y;
            Bs[lkv * 4 + 2][m] = vb.z; Bs[lkv * 4 + 3][m] = vb.w;
        }
        __syncthreads();

        #pragma unroll
        for (int kk = 0; kk < BK; ++kk) {
            float a[8], bb[8];
            *(float4*)&a[0]  = *(const float4*)&As[kk][ty * 8];
            *(float4*)&a[4]  = *(const float4*)&As[kk][ty * 8 + 4];
            *(float4*)&bb[0] = *(const float4*)&Bs[kk][tx * 8];
            *(float4*)&bb[4] = *(const float4*)&Bs[kk][tx * 8 + 4];
            #pragma unroll
            for (int i = 0; i < 8; ++i)
                #pragma unroll
                for (int j = 0; j < 8; ++j) acc[i][j] += a[i] * bb[j];
        }
        __syncthreads();
    }

    #pragma unroll
    for (int i = 0; i < 8; ++i) {
        const int row = bm + ty * 8 + i;
        float* crow = C + (size_t)row * N + bn + tx * 8;
        #pragma unroll
        for (int j = 0; j < 8; ++j) {
            float v = acc[i][j] + bias[bn + tx * 8 + j];
            if (RELU) v = fmaxf(v, 0.f);
            crow[j] = v;
        }
    }
}

// ---------------------------------------------------------------------------
// GRU gates: hnew = (1-z)*n + z*h  (writes fp32 + bf16 copy)
// ---------------------------------------------------------------------------
__global__ __launch_bounds__(256) void gru_gates_kernel(
    const float* __restrict__ gi, const float* __restrict__ gh,
    const float* __restrict__ h, float* __restrict__ hnew,
    unsigned short* __restrict__ hnew_b)
{
    const int i = blockIdx.x * 256 + threadIdx.x;
    const int b = i >> 9, j = i & 511;
    const size_t base = (size_t)b * 1536;
    const float ir = gi[base + j], iz = gi[base + 512 + j], in_ = gi[base + 1024 + j];
    const float hr = gh[base + j], hz = gh[base + 512 + j], hn  = gh[base + 1024 + j];
    const float r = 1.f / (1.f + expf(-(ir + hr)));
    const float z = 1.f / (1.f + expf(-(iz + hz)));
    const float n = tanhf(in_ + r * hn);
    const float hv = (1.f - z) * n + z * h[i];
    hnew[i] = hv;
    hnew_b[i] = f2b(hv);
}

// ---------------------------------------------------------------------------
// merge per-tile softmax partials into per-row (max, 1/sum); 1 wave per row
// ---------------------------------------------------------------------------
__global__ __launch_bounds__(64) void softmax_rowstats_kernel(
    const float* __restrict__ pmax, const float* __restrict__ psum,
    float* __restrict__ rowM, float* __restrict__ rowInvS, int NT)
{
    const int row = blockIdx.x, t = threadIdx.x;
    float Mx = -1e30f, S = 0.f;
    for (int i = t; i < NT; i += 64) {
        const float m = pmax[(size_t)row * NT + i];
        const float s = psum[(size_t)row * NT + i];
        const float nm = fmaxf(Mx, m);
        S = S * expf(Mx - nm) + s * expf(m - nm);
        Mx = nm;
    }
    #pragma unroll
    for (int mask = 1; mask < 64; mask <<= 1) {
        const float m2 = __shfl_xor(Mx, mask);
        const float s2 = __shfl_xor(S, mask);
        const float nm = fmaxf(Mx, m2);
        S = S * expf(Mx - nm) + s2 * expf(m2 - nm);
        Mx = nm;
    }
    if (t == 0) { rowM[row] = Mx; rowInvS[row] = 1.f / S; }
}

// ---------------------------------------------------------------------------
// apply from bf16-packed logits (low half of each fp32 row slot), LDS-staged
// to avoid in-place read/write overlap. out = exp(x - M) * invS, fp32.
// ---------------------------------------------------------------------------
__global__ __launch_bounds__(256) void softmax_apply_bf16_kernel(
    float* logits, const float* __restrict__ rowM,
    const float* __restrict__ rowInvS)
{
    const int row = blockIdx.x, t = threadIdx.x;
    __shared__ unsigned short srow[V];                       // 64000 B
    const unsigned short* lb = (const unsigned short*)logits + (size_t)row * (2 * V);
    for (int i = t; i < V / 8; i += 256)
        *(ushort8*)&srow[i * 8] = *(const ushort8*)&lb[i * 8];
    __syncthreads();
    const float Mx = rowM[row], is = rowInvS[row];
    float* lo = logits + (size_t)row * V;
    for (int i = t; i < V / 4; i += 256) {
        const uint2 u = *(const uint2*)&srow[i * 4];
        const float x0 = __uint_as_float((u.x & 0xffffu) << 16);
        const float x1 = __uint_as_float(u.x & 0xffff0000u);
        const float x2 = __uint_as_float((u.y & 0xffffu) << 16);
        const float x3 = __uint_as_float(u.y & 0xffff0000u);
        float4 v;
        v.x = expf(x0 - Mx) * is;
        v.y = expf(x1 - Mx) * is;
        v.z = expf(x2 - Mx) * is;
        v.w = expf(x3 - Mx) * is;
        *(float4*)&lo[i * 4] = v;
    }
}

// ---------------------------------------------------------------------------
// in-place row softmax (fallback)
// ---------------------------------------------------------------------------
__global__ __launch_bounds__(256) void softmax_rows_kernel(float* __restrict__ logits, int N)
{
    const int b = blockIdx.x, t = threadIdx.x;
    __shared__ float red[256];
    float* row = logits + (size_t)b * N;

    float mx = -1e30f;
    for (int i = t; i < N; i += 256) mx = fmaxf(mx, row[i]);
    red[t] = mx; __syncthreads();
    for (int s = 128; s > 0; s >>= 1) { if (t < s) red[t] = fmaxf(red[t], red[t + s]); __syncthreads(); }
    mx = red[0]; __syncthreads();

    float sum = 0.f;
    for (int i = t; i < N; i += 256) sum += expf(row[i] - mx);
    red[t] = sum; __syncthreads();
    for (int s = 128; s > 0; s >>= 1) { if (t < s) red[t] += red[t + s]; __syncthreads(); }
    const float inv = 1.0f / red[0];
    __syncthreads();

    for (int i = t; i < N; i += 256) row[i] = expf(row[i] - mx) * inv;
}

// ---------------------------------------------------------------------------
extern "C" void kernel_launch(void* const* d_in, const int* in_sizes, int n_in,
                              void* d_out, int out_size, void* d_ws, size_t ws_size,
                              hipStream_t stream)
{
    const int*   tok    = (const int*)d_in[0];
    const float* hidden = (const float*)d_in[1];
    const float* enc    = (const float*)d_in[2];
    const float* emb    = (const float*)d_in[3];
    const float* attn_W = (const float*)d_in[4];
    const float* attn_b = (const float*)d_in[5];
    const float* comb_W = (const float*)d_in[6];
    const float* comb_b = (const float*)d_in[7];
    const float* W_ih   = (const float*)d_in[8];
    const float* W_hh   = (const float*)d_in[9];
    const float* b_ih   = (const float*)d_in[10];
    const float* b_hh   = (const float*)d_in[11];
    const float* out_W  = (const float*)d_in[12];
    const float* out_b  = (const float*)d_in[13];

    float* out   = (float*)d_out;
    float* pred  = out;                             // B*V
    float* hid_o = out + (size_t)B * V;             // NL*B*H
    float* attnw = hid_o + (size_t)NL * B * H;      // B*MAXLEN

    // fp32 scratch carved from pred region (dead until the logits GEMM)
    float* q  = pred;                               // B*1024
    float* c2 = q  + (size_t)B * 1024;              // B*1024
    float* gi = c2 + (size_t)B * 1024;              // B*1536
    float* gh = gi + (size_t)B * 1536;              // B*1536

    // bf16 scratch (still inside pred region)
    unsigned short* sb     = (unsigned short*)(gh + (size_t)B * 1536);
    unsigned short* c2b    = sb;                            // B*1024
    unsigned short* xb     = c2b  + (size_t)B * 1024;       // B*512
    unsigned short* h01b   = xb   + (size_t)B * 512;        // NL*B*512
    unsigned short* hn0b   = h01b + (size_t)NL * B * 512;   // B*512
    unsigned short* Wihb   = hn0b + (size_t)B * 512;        // 2*1536*512
    unsigned short* Whhb   = Wihb + (size_t)NL * 1536 * 512;
    unsigned short* combWb = Whhb + (size_t)NL * 1536 * 512; // 512*1024
    unsigned short* hn1b_fallback = combWb + (size_t)512 * 1024;

    // final-GEMM inputs + softmax partials live in d_ws (outside pred region)
    const size_t outWb_e = (size_t)V * H;           // 16,384,000
    const size_t hn1b_e  = (size_t)B * H;           //  2,097,152
    const int    NT      = V / 128;                 // 250
    const size_t bf_bytes = (outWb_e + hn1b_e) * sizeof(unsigned short);
    const size_t pt_bytes = ((size_t)B * NT * 2 + 2 * B) * sizeof(float);
    const bool lvl1 = ws_size >= bf_bytes;                 // bf16 logits GEMM
    const bool lvl2 = ws_size >= bf_bytes + pt_bytes;      // + fused partials

    unsigned short* outWb = (unsigned short*)d_ws;
    unsigned short* hn1b  = lvl1 ? outWb + outWb_e : hn1b_fallback;
    float* pmax_g  = (float*)((char*)d_ws + bf_bytes);
    float* psum_g  = pmax_g + (size_t)B * NT;
    float* rowM    = psum_g + (size_t)B * NT;
    float* rowInvS = rowM + B;

    unsigned short* h0b = h01b;
    unsigned short* h1b = h01b + (size_t)B * 512;

    embed_concat_kernel<<<B, 256, 0, stream>>>(tok, emb, hidden, q, c2);
    attn_fused_kernel<<<B, 256, 0, stream>>>(q, attn_W, attn_b, enc, attnw, c2);

    // conversions (all sizes divisible by 2048)
    f32_to_bf16_kernel<<<(B * 1024) / 2048, 256, 0, stream>>>(c2, c2b);
    f32_to_bf16_kernel<<<(512 * 1024) / 2048, 256, 0, stream>>>(comb_W, combWb);
    f32_to_bf16_kernel<<<(NL * 1536 * 512) / 2048, 256, 0, stream>>>(W_ih, Wihb);
    f32_to_bf16_kernel<<<(NL * 1536 * 512) / 2048, 256, 0, stream>>>(W_hh, Whhb);
    f32_to_bf16_kernel<<<(NL * B * 512) / 2048, 256, 0, stream>>>(hidden, h01b);
    if (lvl1)
        f32_to_bf16_kernel<<<(V * 512) / 2048, 256, 0, stream>>>(out_W, outWb);

    // x = relu(c2 @ combine_W.T + b)   [4096 x 512 x 1024] -> bf16
    gemm_bf16_nt<1, 1, 0, 0><<<dim3(512 / 128, B / 128), 256, 0, stream>>>(
        c2b, combWb, comb_b, xb, B, 512, 1024, 512, nullptr, nullptr);

    // GRU layer 0
    gemm_bf16_nt<0, 0, 0, 0><<<dim3(1536 / 128, B / 128), 256, 0, stream>>>(
        xb, Wihb, b_ih, gi, B, 1536, 512, 1536, nullptr, nullptr);
    gemm_bf16_nt<0, 0, 0, 0><<<dim3(1536 / 128, B / 128), 256, 0, stream>>>(
        h0b, Whhb, b_hh, gh, B, 1536, 512, 1536, nullptr, nullptr);
    gru_gates_kernel<<<(B * H) / 256, 256, 0, stream>>>(gi, gh, hidden, hid_o, hn0b);

    // GRU layer 1
    gemm_bf16_nt<0, 0, 0, 0><<<dim3(1536 / 128, B / 128), 256, 0, stream>>>(
        hn0b, Wihb + (size_t)1536 * 512, b_ih + 1536, gi, B, 1536, 512, 1536, nullptr, nullptr);
    gemm_bf16_nt<0, 0, 0, 0><<<dim3(1536 / 128, B / 128), 256, 0, stream>>>(
        h1b, Whhb + (size_t)1536 * 512, b_hh + 1536, gh, B, 1536, 512, 1536, nullptr, nullptr);
    gru_gates_kernel<<<(B * H) / 256, 256, 0, stream>>>(
        gi, gh, hidden + (size_t)B * H, hid_o + (size_t)B * H, hn1b);

    // logits = h1 @ out_W.T + out_b   [4096 x 32000 x 512], then softmax
    if (lvl2) {
        // bf16 logits packed into low half of each fp32 row slot (ldc = 2V
        // ushorts); partials fused in epilogue; XCD-chunked block swizzle.
        gemm_bf16_nt<0, 1, 1, 1><<<(B / 128) * (V / 128), 256, 0, stream>>>(
            hn1b, outWb, out_b, pred, B, V, 512, 2 * V, pmax_g, psum_g);
        softmax_rowstats_kernel<<<B, 64, 0, stream>>>(pmax_g, psum_g, rowM, rowInvS, NT);
        softmax_apply_bf16_kernel<<<B, 256, 0, stream>>>(pred, rowM, rowInvS);
    } else if (lvl1) {
        gemm_bf16_nt<0, 0, 0, 1><<<(B / 128) * (V / 128), 256, 0, stream>>>(
            hn1b, outWb, out_b, pred, B, V, 512, V, nullptr, nullptr);
        softmax_rows_kernel<<<B, 256, 0, stream>>>(pred, V);
    } else {
        gemm_nt<0><<<dim3(V / 128, B / 128), 256, 0, stream>>>(
            hid_o + (size_t)B * H, out_W, out_b, pred, B, V, 512);
        softmax_rows_kernel<<<B, 256, 0, stream>>>(pred, V);
    }
}

// Round 6
// 923.776 us; speedup vs baseline: 1.1299x; 1.1299x over previous
//
#include <hip/hip_runtime.h>
#include <cstdint>
#include <cstddef>
#include <cmath>

#define B 4096
#define H 512
#define E 512
#define V 32000
#define NL 2
#define MAXLEN 99

typedef __attribute__((ext_vector_type(8))) short  bf16x8;
typedef __attribute__((ext_vector_type(4))) float  f32x4;
typedef __attribute__((ext_vector_type(8))) unsigned short ushort8;

__device__ __forceinline__ unsigned short f2b(float x) {
    union { float f; unsigned u; } c; c.f = x;
    unsigned r = c.u + 0x7fff + ((c.u >> 16) & 1);   // RNE to bf16
    return (unsigned short)(r >> 16);
}
__device__ __forceinline__ float b2f(unsigned short u) {
    return __uint_as_float((unsigned)u << 16);
}

#define GLOAD16(gp, lp)                                                        \
    __builtin_amdgcn_global_load_lds(                                          \
        (const __attribute__((address_space(1))) void*)(gp),                   \
        (__attribute__((address_space(3))) void*)(lp), 16, 0, 0)

// ---------------------------------------------------------------------------
// embed gather + build q = [emb, hidden0] and c2[:, :512] = emb
// ---------------------------------------------------------------------------
__global__ __launch_bounds__(256) void embed_concat_kernel(
    const int* __restrict__ tok, const float* __restrict__ emb,
    const float* __restrict__ hidden0, float* __restrict__ q, float* __restrict__ c2)
{
    const int b = blockIdx.x, t = threadIdx.x;
    const int v = tok[b];
    const float2 e = ((const float2*)(emb + (size_t)v * E))[t];
    ((float2*)(q  + (size_t)b * 1024))[t] = e;
    ((float2*)(c2 + (size_t)b * 1024))[t] = e;
    const float2 h = ((const float2*)(hidden0 + (size_t)b * H))[t];
    ((float2*)(q + (size_t)b * 1024 + 512))[t] = h;
}

// ---------------------------------------------------------------------------
// per-row attention: logits + softmax + weighted encoder sum
// ---------------------------------------------------------------------------
__global__ __launch_bounds__(256) void attn_fused_kernel(
    const float* __restrict__ q, const float* __restrict__ attn_W,
    const float* __restrict__ attn_b, const float* __restrict__ enc,
    float* __restrict__ attnw, float* __restrict__ c2)
{
    const int b = blockIdx.x, t = threadIdx.x;
    __shared__ float qs[1024];
    __shared__ float ls[128];

    ((float4*)qs)[t] = ((const float4*)(q + (size_t)b * 1024))[t];
    __syncthreads();

    float s = -1e30f;
    if (t < MAXLEN) {
        const float4* w4 = (const float4*)(attn_W + (size_t)t * 1024);
        const float4* q4 = (const float4*)qs;
        float ax = 0.f, ay = 0.f, az = 0.f, aw = 0.f;
        #pragma unroll 8
        for (int k = 0; k < 256; ++k) {
            const float4 a = q4[k], w = w4[k];
            ax += a.x * w.x; ay += a.y * w.y; az += a.z * w.z; aw += a.w * w.w;
        }
        s = (ax + ay) + (az + aw) + attn_b[t];
    }
    if (t < 128) ls[t] = s;
    __syncthreads();

    float mx = -1e30f;
    for (int i = 0; i < 128; ++i) mx = fmaxf(mx, ls[i]);
    __syncthreads();

    float ex = 0.f;
    if (t < MAXLEN) ex = expf(s - mx);
    if (t < 128) ls[t] = ex;
    __syncthreads();

    float sum = 0.f;
    for (int i = 0; i < 128; ++i) sum += ls[i];
    const float inv = 1.0f / sum;

    if (t < MAXLEN) attnw[(size_t)b * MAXLEN + t] = ex * inv;

    float accx = 0.f, accy = 0.f;
    const float2* encb = (const float2*)(enc + (size_t)b * MAXLEN * H);
    for (int l = 0; l < MAXLEN; ++l) {
        const float wl = ls[l];
        const float2 ev = encb[(size_t)l * 256 + t];
        accx += wl * ev.x; accy += wl * ev.y;
    }
    float2 outv; outv.x = accx * inv; outv.y = accy * inv;
    ((float2*)(c2 + (size_t)b * 1024 + 512))[t] = outv;
}

// ---------------------------------------------------------------------------
// fp32 -> bf16 conversion, 8 elems/thread, exact grid (n % 2048 == 0)
// ---------------------------------------------------------------------------
__global__ __launch_bounds__(256) void f32_to_bf16_kernel(
    const float* __restrict__ in, unsigned short* __restrict__ out)
{
    const size_t i = ((size_t)blockIdx.x * 256 + threadIdx.x) * 8;
    const float4 a = *(const float4*)(in + i);
    const float4 b = *(const float4*)(in + i + 4);
    ushort8 o;
    o[0] = f2b(a.x); o[1] = f2b(a.y); o[2] = f2b(a.z); o[3] = f2b(a.w);
    o[4] = f2b(b.x); o[5] = f2b(b.y); o[6] = f2b(b.z); o[7] = f2b(b.w);
    *(ushort8*)(out + i) = o;
}

// ---------------------------------------------------------------------------
// bf16 MFMA NT GEMM: C[m,n] = A[m,:] . W[n,:] + bias[n]
// BM=BN=128, BK=32, 256 thr (4 waves, 2x2 of 64x64), m97-class structure.
// OUTBF=1: LDS-staged dense bf16 epilogue (full-sector ushort8 stores).
// PARTIALS: per-(row, 128-col tile) softmax partials (max, sum-exp).
// GSWAP: blockIdx.x indexes M-tiles (consecutive blocks share W-panel).
// ldc = output row stride in OUTPUT elements; colOff = column offset added
// to the output column index (used to pack logits in top half of row slot).
// ---------------------------------------------------------------------------
template<int RELU, int OUTBF, int PARTIALS, int GSWAP>
__global__ __launch_bounds__(256) void gemm_bf16_nt(
    const unsigned short* __restrict__ A, const unsigned short* __restrict__ Wb,
    const float* __restrict__ bias, void* __restrict__ Cv,
    int M, int N, int K, int ldc, int colOff,
    float* __restrict__ pmax_g, float* __restrict__ psum_g)
{
    __shared__ __align__(16) unsigned short As[2][4096];   // [buf][64 rows][32 k]x2
    __shared__ __align__(16) unsigned short Bs[2][4096];

    const int tid  = threadIdx.x;
    const int bn   = (GSWAP ? blockIdx.y : blockIdx.x) * 128;
    const int bm   = (GSWAP ? blockIdx.x : blockIdx.y) * 128;
    const int lane = tid & 63;
    const int wid  = tid >> 6;
    const int wr   = (wid >> 1) * 64;      // wave row offset in tile
    const int wc   = (wid & 1) * 64;       // wave col offset in tile
    const int fr   = lane & 15;            // fragment row/col within 16
    const int fk   = (lane >> 4) * 8;      // k-elem offset (8 bf16 = 16B)

    f32x4 acc[4][4];
    #pragma unroll
    for (int m = 0; m < 4; ++m)
        #pragma unroll
        for (int n = 0; n < 4; ++n) acc[m][n] = (f32x4)0.f;

    const int srow = tid >> 2;             // 0..63
    const int sk   = (tid & 3) * 8;        // 0,8,16,24

    const unsigned short* ga = A  + (size_t)(bm + srow) * K + sk;
    const unsigned short* gb = Wb + (size_t)(bn + srow) * K + sk;

    // prologue: stage k0=0 into buf 0
    {
        GLOAD16(ga,                    &As[0][tid * 8]);
        GLOAD16(ga + (size_t)64 * K,   &As[0][2048 + tid * 8]);
        GLOAD16(gb,                    &Bs[0][tid * 8]);
        GLOAD16(gb + (size_t)64 * K,   &Bs[0][2048 + tid * 8]);
    }

    int buf = 0;
    for (int k0 = 0; k0 < K; k0 += 32) {
        __syncthreads();                   // staged loads for `buf` complete

        if (k0 + 32 < K) {                 // prefetch next into buf^1
            const int nb = buf ^ 1;
            GLOAD16(ga + k0 + 32,                  &As[nb][tid * 8]);
            GLOAD16(ga + k0 + 32 + (size_t)64 * K, &As[nb][2048 + tid * 8]);
            GLOAD16(gb + k0 + 32,                  &Bs[nb][tid * 8]);
            GLOAD16(gb + k0 + 32 + (size_t)64 * K, &Bs[nb][2048 + tid * 8]);
        }

        bf16x8 af[4], bf_[4];
        #pragma unroll
        for (int m = 0; m < 4; ++m)
            af[m] = *(const bf16x8*)&As[buf][(wr + m * 16 + fr) * 32 + fk];
        #pragma unroll
        for (int n = 0; n < 4; ++n)
            bf_[n] = *(const bf16x8*)&Bs[buf][(wc + n * 16 + fr) * 32 + fk];

        #pragma unroll
        for (int m = 0; m < 4; ++m)
            #pragma unroll
            for (int n = 0; n < 4; ++n)
                acc[m][n] = __builtin_amdgcn_mfma_f32_16x16x32_bf16(
                    af[m], bf_[n], acc[m][n], 0, 0, 0);

        buf ^= 1;
    }

    // per-lane bias for its 4 column fragments
    float bv[4];
    #pragma unroll
    for (int n = 0; n < 4; ++n) bv[n] = bias[bn + wc + n * 16 + fr];

    if constexpr (PARTIALS) {
        __shared__ float pm_s[2][2][64];
        __shared__ float ps_s[2][2][64];
        const int wrIdx = wid >> 1, wcIdx = wid & 1;

        #pragma unroll
        for (int m = 0; m < 4; ++m) {
            #pragma unroll
            for (int r = 0; r < 4; ++r) {
                float vmax = -1e30f;
                #pragma unroll
                for (int n = 0; n < 4; ++n) vmax = fmaxf(vmax, acc[m][n][r] + bv[n]);
                vmax = fmaxf(vmax, __shfl_xor(vmax, 1));
                vmax = fmaxf(vmax, __shfl_xor(vmax, 2));
                vmax = fmaxf(vmax, __shfl_xor(vmax, 4));
                vmax = fmaxf(vmax, __shfl_xor(vmax, 8));
                float vsum = 0.f;
                #pragma unroll
                for (int n = 0; n < 4; ++n) vsum += expf(acc[m][n][r] + bv[n] - vmax);
                vsum += __shfl_xor(vsum, 1);
                vsum += __shfl_xor(vsum, 2);
                vsum += __shfl_xor(vsum, 4);
                vsum += __shfl_xor(vsum, 8);
                const int rowh = m * 16 + (lane >> 4) * 4 + r;
                if (fr == 0) { pm_s[wrIdx][wcIdx][rowh] = vmax; ps_s[wrIdx][wcIdx][rowh] = vsum; }
            }
        }
        __syncthreads();
        if (wcIdx == 0) {
            const float m0 = pm_s[wrIdx][0][lane], m1 = pm_s[wrIdx][1][lane];
            const float s0 = ps_s[wrIdx][0][lane], s1 = ps_s[wrIdx][1][lane];
            const float Mx = fmaxf(m0, m1);
            const float S  = s0 * expf(m0 - Mx) + s1 * expf(m1 - Mx);
            const int row = bm + wr + lane;
            const int nt  = bn >> 7;
            const int NT  = N >> 7;
            pmax_g[(size_t)row * NT + nt] = Mx;
            psum_g[(size_t)row * NT + nt] = S;
        }
    }

    if constexpr (OUTBF) {
        // Dense-sector bf16 epilogue: stage tile in the dead A/B LDS buffers
        // (rows 0-63 -> As, 64-127 -> Bs; XOR swizzle (row&12)<<3 cuts write
        // bank conflicts), then store full 16B ushort8 runs.
        __syncthreads();                   // K-loop LDS reads all done
        unsigned short* smb = (wr == 0) ? (unsigned short*)As : (unsigned short*)Bs;
        #pragma unroll
        for (int m = 0; m < 4; ++m) {
            #pragma unroll
            for (int n = 0; n < 4; ++n) {
                #pragma unroll
                for (int r = 0; r < 4; ++r) {
                    float v = acc[m][n][r] + bv[n];
                    if (RELU) v = fmaxf(v, 0.f);
                    const int row  = m * 16 + (lane >> 4) * 4 + r;   // 0..63 in half
                    const int col  = wc + n * 16 + fr;
                    const int cc   = col ^ ((row & 12) << 3);
                    smb[row * 128 + cc] = f2b(v);
                }
            }
        }
        __syncthreads();
        unsigned short* Cb = (unsigned short*)Cv;
        const int rrow = tid >> 4;          // 0..15
        const int cch  = (tid & 15) * 8;    // col chunk base
        #pragma unroll
        for (int p = 0; p < 8; ++p) {
            const int row  = p * 16 + rrow;
            const int lrow = row & 63;
            unsigned short* smr = (p < 4) ? (unsigned short*)As : (unsigned short*)Bs;
            const int cc = cch ^ ((row & 12) << 3);
            const ushort8 v = *(const ushort8*)&smr[lrow * 128 + cc];
            *(ushort8*)&Cb[(size_t)(bm + row) * ldc + colOff + bn + cch] = v;
        }
    } else {
        // scattered fp32 stores (64B-sector segments)
        float* Cf = (float*)Cv;
        #pragma unroll
        for (int m = 0; m < 4; ++m) {
            #pragma unroll
            for (int n = 0; n < 4; ++n) {
                const int col = bn + wc + n * 16 + fr;
                const int row = bm + wr + m * 16 + (lane >> 4) * 4;
                #pragma unroll
                for (int r = 0; r < 4; ++r) {
                    float v = acc[m][n][r] + bv[n];
                    if (RELU) v = fmaxf(v, 0.f);
                    Cf[(size_t)(row + r) * ldc + colOff + col] = v;
                }
            }
        }
    }
}

// ---------------------------------------------------------------------------
// fp32 NT GEMM (fallback for logits if ws too small)
// ---------------------------------------------------------------------------
template<int RELU>
__global__ __launch_bounds__(256) void gemm_nt(
    const float* __restrict__ A, const float* __restrict__ W,
    const float* __restrict__ bias, float* __restrict__ C,
    int M, int N, int K)
{
    constexpr int BM = 128, BN = 128, BK = 32;
    __shared__ float As[BK][BM + 4];
    __shared__ float Bs[BK][BN + 4];

    const int tid = threadIdx.x;
    const int bn = blockIdx.x * BN;
    const int bm = blockIdx.y * BM;
    const int tx = tid & 15;
    const int ty = tid >> 4;

    float acc[8][8];
    #pragma unroll
    for (int i = 0; i < 8; ++i)
        #pragma unroll
        for (int j = 0; j < 8; ++j) acc[i][j] = 0.f;

    const int lkv = tid & 7;
    const int lm0 = tid >> 3;

    for (int k0 = 0; k0 < K; k0 += BK) {
        #pragma unroll
        for (int r = 0; r < 4; ++r) {
            const int m = lm0 + 32 * r;
            const float4 va = *(const float4*)(A + (size_t)(bm + m) * K + k0 + lkv * 4);
            As[lkv * 4 + 0][m] = va.x; As[lkv * 4 + 1][m] = va.y;
            As[lkv * 4 + 2][m] = va.z; As[lkv * 4 + 3][m] = va.w;
            const float4 vb = *(const float4*)(W + (size_t)(bn + m) * K + k0 + lkv * 4);
            Bs[lkv * 4 + 0][m] = vb.x; Bs[lkv * 4 + 1][m] = vb.y;
            Bs[lkv * 4 + 2][m] = vb.z; Bs[lkv * 4 + 3][m] = vb.w;
        }
        __syncthreads();

        #pragma unroll
        for (int kk = 0; kk < BK; ++kk) {
            float a[8], bb[8];
            *(float4*)&a[0]  = *(const float4*)&As[kk][ty * 8];
            *(float4*)&a[4]  = *(const float4*)&As[kk][ty * 8 + 4];
            *(float4*)&bb[0] = *(const float4*)&Bs[kk][tx * 8];
            *(float4*)&bb[4] = *(const float4*)&Bs[kk][tx * 8 + 4];
            #pragma unroll
            for (int i = 0; i < 8; ++i)
                #pragma unroll
                for (int j = 0; j < 8; ++j) acc[i][j] += a[i] * bb[j];
        }
        __syncthreads();
    }

    #pragma unroll
    for (int i = 0; i < 8; ++i) {
        const int row = bm + ty * 8 + i;
        float* crow = C + (size_t)row * N + bn + tx * 8;
        #pragma unroll
        for (int j = 0; j < 8; ++j) {
            float v = acc[i][j] + bias[bn + tx * 8 + j];
            if (RELU) v = fmaxf(v, 0.f);
            crow[j] = v;
        }
    }
}

// ---------------------------------------------------------------------------
// GRU gates from bf16 gi/gh: hnew = (1-z)*n + z*h  (fp32 + bf16 outputs)
// ---------------------------------------------------------------------------
__global__ __launch_bounds__(256) void gru_gates_kernel(
    const unsigned short* __restrict__ gi, const unsigned short* __restrict__ gh,
    const float* __restrict__ h, float* __restrict__ hnew,
    unsigned short* __restrict__ hnew_b)
{
    const int i = blockIdx.x * 256 + threadIdx.x;
    const int b = i >> 9, j = i & 511;
    const size_t base = (size_t)b * 1536;
    const float ir = b2f(gi[base + j]), iz = b2f(gi[base + 512 + j]), in_ = b2f(gi[base + 1024 + j]);
    const float hr = b2f(gh[base + j]), hz = b2f(gh[base + 512 + j]), hn  = b2f(gh[base + 1024 + j]);
    const float r = 1.f / (1.f + expf(-(ir + hr)));
    const float z = 1.f / (1.f + expf(-(iz + hz)));
    const float n = tanhf(in_ + r * hn);
    const float hv = (1.f - z) * n + z * h[i];
    hnew[i] = hv;
    hnew_b[i] = f2b(hv);
}

// ---------------------------------------------------------------------------
// merge per-tile softmax partials into per-row (max, 1/sum); 1 wave per row
// ---------------------------------------------------------------------------
__global__ __launch_bounds__(64) void softmax_rowstats_kernel(
    const float* __restrict__ pmax, const float* __restrict__ psum,
    float* __restrict__ rowM, float* __restrict__ rowInvS, int NT)
{
    const int row = blockIdx.x, t = threadIdx.x;
    float Mx = -1e30f, S = 0.f;
    for (int i = t; i < NT; i += 64) {
        const float m = pmax[(size_t)row * NT + i];
        const float s = psum[(size_t)row * NT + i];
        const float nm = fmaxf(Mx, m);
        S = S * expf(Mx - nm) + s * expf(m - nm);
        Mx = nm;
    }
    #pragma unroll
    for (int mask = 1; mask < 64; mask <<= 1) {
        const float m2 = __shfl_xor(Mx, mask);
        const float s2 = __shfl_xor(S, mask);
        const float nm = fmaxf(Mx, m2);
        S = S * expf(Mx - nm) + s2 * expf(m2 - nm);
        Mx = nm;
    }
    if (t == 0) { rowM[row] = Mx; rowInvS[row] = 1.f / S; }
}

// ---------------------------------------------------------------------------
// apply from bf16 logits packed in the TOP half of each fp32 row slot.
// Register-staged (no LDS): all reads before any write within the block.
// ---------------------------------------------------------------------------
__global__ __launch_bounds__(256) void softmax_apply_tophalf_kernel(
    float* logits, const float* __restrict__ rowM,
    const float* __restrict__ rowInvS)
{
    const int row = blockIdx.x, t = threadIdx.x;
    const float Mx = rowM[row], is = rowInvS[row];
    const unsigned short* src = (const unsigned short*)logits + (size_t)row * (2 * V) + V;
    ushort8 buf[16];
    #pragma unroll
    for (int k = 0; k < 16; ++k) {
        const int i = t + 256 * k;              // chunk over V/8 = 4000
        if (i < V / 8) buf[k] = *(const ushort8*)&src[i * 8];
    }
    __syncthreads();                            // all reads done before writes
    float* dst = logits + (size_t)row * V;
    #pragma unroll
    for (int k = 0; k < 16; ++k) {
        const int i = t + 256 * k;
        if (i < V / 8) {
            float4 o0, o1;
            o0.x = expf(b2f(buf[k][0]) - Mx) * is;
            o0.y = expf(b2f(buf[k][1]) - Mx) * is;
            o0.z = expf(b2f(buf[k][2]) - Mx) * is;
            o0.w = expf(b2f(buf[k][3]) - Mx) * is;
            o1.x = expf(b2f(buf[k][4]) - Mx) * is;
            o1.y = expf(b2f(buf[k][5]) - Mx) * is;
            o1.z = expf(b2f(buf[k][6]) - Mx) * is;
            o1.w = expf(b2f(buf[k][7]) - Mx) * is;
            *(float4*)&dst[i * 8]     = o0;
            *(float4*)&dst[i * 8 + 4] = o1;
        }
    }
}

// ---------------------------------------------------------------------------
// in-place row softmax (fallback)
// ---------------------------------------------------------------------------
__global__ __launch_bounds__(256) void softmax_rows_kernel(float* __restrict__ logits, int N)
{
    const int b = blockIdx.x, t = threadIdx.x;
    __shared__ float red[256];
    float* row = logits + (size_t)b * N;

    float mx = -1e30f;
    for (int i = t; i < N; i += 256) mx = fmaxf(mx, row[i]);
    red[t] = mx; __syncthreads();
    for (int s = 128; s > 0; s >>= 1) { if (t < s) red[t] = fmaxf(red[t], red[t + s]); __syncthreads(); }
    mx = red[0]; __syncthreads();

    float sum = 0.f;
    for (int i = t; i < N; i += 256) sum += expf(row[i] - mx);
    red[t] = sum; __syncthreads();
    for (int s = 128; s > 0; s >>= 1) { if (t < s) red[t] += red[t + s]; __syncthreads(); }
    const float inv = 1.0f / red[0];
    __syncthreads();

    for (int i = t; i < N; i += 256) row[i] = expf(row[i] - mx) * inv;
}

// ---------------------------------------------------------------------------
extern "C" void kernel_launch(void* const* d_in, const int* in_sizes, int n_in,
                              void* d_out, int out_size, void* d_ws, size_t ws_size,
                              hipStream_t stream)
{
    const int*   tok    = (const int*)d_in[0];
    const float* hidden = (const float*)d_in[1];
    const float* enc    = (const float*)d_in[2];
    const float* emb    = (const float*)d_in[3];
    const float* attn_W = (const float*)d_in[4];
    const float* attn_b = (const float*)d_in[5];
    const float* comb_W = (const float*)d_in[6];
    const float* comb_b = (const float*)d_in[7];
    const float* W_ih   = (const float*)d_in[8];
    const float* W_hh   = (const float*)d_in[9];
    const float* b_ih   = (const float*)d_in[10];
    const float* b_hh   = (const float*)d_in[11];
    const float* out_W  = (const float*)d_in[12];
    const float* out_b  = (const float*)d_in[13];

    float* out   = (float*)d_out;
    float* pred  = out;                             // B*V
    float* hid_o = out + (size_t)B * V;             // NL*B*H
    float* attnw = hid_o + (size_t)NL * B * H;      // B*MAXLEN

    // fp32 scratch carved from pred region (dead until the logits GEMM)
    float* q  = pred;                               // B*1024
    float* c2 = q  + (size_t)B * 1024;              // B*1024

    // bf16 scratch (still inside pred region)
    unsigned short* sb     = (unsigned short*)(c2 + (size_t)B * 1024);
    unsigned short* c2b    = sb;                            // B*1024
    unsigned short* xb     = c2b  + (size_t)B * 1024;       // B*512
    unsigned short* h01b   = xb   + (size_t)B * 512;        // NL*B*512
    unsigned short* hn0b   = h01b + (size_t)NL * B * 512;   // B*512
    unsigned short* gi_b   = hn0b + (size_t)B * 512;        // B*1536
    unsigned short* gh_b   = gi_b + (size_t)B * 1536;       // B*1536
    unsigned short* Wihb   = gh_b + (size_t)B * 1536;       // 2*1536*512
    unsigned short* Whhb   = Wihb + (size_t)NL * 1536 * 512;
    unsigned short* combWb = Whhb + (size_t)NL * 1536 * 512; // 512*1024
    unsigned short* hn1b_fallback = combWb + (size_t)512 * 1024;

    // final-GEMM inputs + softmax partials live in d_ws (outside pred region)
    const size_t outWb_e = (size_t)V * H;           // 16,384,000
    const size_t hn1b_e  = (size_t)B * H;           //  2,097,152
    const int    NT      = V / 128;                 // 250
    const size_t bf_bytes = (outWb_e + hn1b_e) * sizeof(unsigned short);
    const size_t pt_bytes = ((size_t)B * NT * 2 + 2 * B) * sizeof(float);
    const bool lvl1 = ws_size >= bf_bytes;                 // bf16 logits GEMM
    const bool lvl2 = ws_size >= bf_bytes + pt_bytes;      // + fused partials

    unsigned short* outWb = (unsigned short*)d_ws;
    unsigned short* hn1b  = lvl1 ? outWb + outWb_e : hn1b_fallback;
    float* pmax_g  = (float*)((char*)d_ws + bf_bytes);
    float* psum_g  = pmax_g + (size_t)B * NT;
    float* rowM    = psum_g + (size_t)B * NT;
    float* rowInvS = rowM + B;

    unsigned short* h0b = h01b;
    unsigned short* h1b = h01b + (size_t)B * 512;

    embed_concat_kernel<<<B, 256, 0, stream>>>(tok, emb, hidden, q, c2);
    attn_fused_kernel<<<B, 256, 0, stream>>>(q, attn_W, attn_b, enc, attnw, c2);

    // conversions (all sizes divisible by 2048)
    f32_to_bf16_kernel<<<(B * 1024) / 2048, 256, 0, stream>>>(c2, c2b);
    f32_to_bf16_kernel<<<(512 * 1024) / 2048, 256, 0, stream>>>(comb_W, combWb);
    f32_to_bf16_kernel<<<(NL * 1536 * 512) / 2048, 256, 0, stream>>>(W_ih, Wihb);
    f32_to_bf16_kernel<<<(NL * 1536 * 512) / 2048, 256, 0, stream>>>(W_hh, Whhb);
    f32_to_bf16_kernel<<<(NL * B * 512) / 2048, 256, 0, stream>>>(hidden, h01b);
    if (lvl1)
        f32_to_bf16_kernel<<<(V * 512) / 2048, 256, 0, stream>>>(out_W, outWb);

    // x = relu(c2 @ combine_W.T + b)   [4096 x 512 x 1024] -> bf16 dense
    gemm_bf16_nt<1, 1, 0, 0><<<dim3(512 / 128, B / 128), 256, 0, stream>>>(
        c2b, combWb, comb_b, xb, B, 512, 1024, 512, 0, nullptr, nullptr);

    // GRU layer 0 (gi/gh as dense bf16)
    gemm_bf16_nt<0, 1, 0, 0><<<dim3(1536 / 128, B / 128), 256, 0, stream>>>(
        xb, Wihb, b_ih, gi_b, B, 1536, 512, 1536, 0, nullptr, nullptr);
    gemm_bf16_nt<0, 1, 0, 0><<<dim3(1536 / 128, B / 128), 256, 0, stream>>>(
        h0b, Whhb, b_hh, gh_b, B, 1536, 512, 1536, 0, nullptr, nullptr);
    gru_gates_kernel<<<(B * H) / 256, 256, 0, stream>>>(gi_b, gh_b, hidden, hid_o, hn0b);

    // GRU layer 1
    gemm_bf16_nt<0, 1, 0, 0><<<dim3(1536 / 128, B / 128), 256, 0, stream>>>(
        hn0b, Wihb + (size_t)1536 * 512, b_ih + 1536, gi_b, B, 1536, 512, 1536, 0, nullptr, nullptr);
    gemm_bf16_nt<0, 1, 0, 0><<<dim3(1536 / 128, B / 128), 256, 0, stream>>>(
        h1b, Whhb + (size_t)1536 * 512, b_hh + 1536, gh_b, B, 1536, 512, 1536, 0, nullptr, nullptr);
    gru_gates_kernel<<<(B * H) / 256, 256, 0, stream>>>(
        gi_b, gh_b, hidden + (size_t)B * H, hid_o + (size_t)B * H, hn1b);

    // logits = h1 @ out_W.T + out_b   [4096 x 32000 x 512], then softmax
    if (lvl2) {
        // bf16 logits packed DENSE in the top half of each fp32 row slot
        // (ldc = 2V ushorts, colOff = V); partials fused; GRIDSWAP grid.
        gemm_bf16_nt<0, 1, 1, 1><<<dim3(B / 128, V / 128), 256, 0, stream>>>(
            hn1b, outWb, out_b, pred, B, V, 512, 2 * V, V, pmax_g, psum_g);
        softmax_rowstats_kernel<<<B, 64, 0, stream>>>(pmax_g, psum_g, rowM, rowInvS, NT);
        softmax_apply_tophalf_kernel<<<B, 256, 0, stream>>>(pred, rowM, rowInvS);
    } else if (lvl1) {
        gemm_bf16_nt<0, 0, 0, 1><<<dim3(B / 128, V / 128), 256, 0, stream>>>(
            hn1b, outWb, out_b, pred, B, V, 512, V, 0, nullptr, nullptr);
        softmax_rows_kernel<<<B, 256, 0, stream>>>(pred, V);
    } else {
        gemm_nt<0><<<dim3(V / 128, B / 128), 256, 0, stream>>>(
            hid_o + (size_t)B * H, out_W, out_b, pred, B, V, 512);
        softmax_rows_kernel<<<B, 256, 0, stream>>>(pred, V);
    }
}

// Round 8
// 873.735 us; speedup vs baseline: 1.1946x; 1.0573x over previous
//
#include <hip/hip_runtime.h>
#include <cstdint>
#include <cstddef>
#include <cmath>

#define B 4096
#define H 512
#define E 512
#define V 32000
#define NL 2
#define MAXLEN 99

typedef __attribute__((ext_vector_type(8))) short  bf16x8;
typedef __attribute__((ext_vector_type(4))) float  f32x4;
typedef __attribute__((ext_vector_type(8))) unsigned short ushort8;

__device__ __forceinline__ unsigned short f2b(float x) {
    union { float f; unsigned u; } c; c.f = x;
    unsigned r = c.u + 0x7fff + ((c.u >> 16) & 1);   // RNE to bf16
    return (unsigned short)(r >> 16);
}
__device__ __forceinline__ float b2f(unsigned short u) {
    return __uint_as_float((unsigned)u << 16);
}

#define GLOAD16(gp, lp)                                                        \
    __builtin_amdgcn_global_load_lds(                                          \
        (const __attribute__((address_space(1))) void*)(gp),                   \
        (__attribute__((address_space(3))) void*)(lp), 16, 0, 0)

// ---------------------------------------------------------------------------
// FUSED embed + attention: block b gathers emb[tok[b]] + hidden0[b] into LDS,
// computes attn logits/softmax/weighted-enc-sum, writes attnw (fp32 output)
// and c2b = [emb | attn_applied] directly in bf16.
// ---------------------------------------------------------------------------
__global__ __launch_bounds__(256) void embed_attn_kernel(
    const int* __restrict__ tok, const float* __restrict__ emb,
    const float* __restrict__ hidden0, const float* __restrict__ attn_W,
    const float* __restrict__ attn_b, const float* __restrict__ enc,
    float* __restrict__ attnw, unsigned short* __restrict__ c2b)
{
    const int b = blockIdx.x, t = threadIdx.x;
    __shared__ float qs[1024];
    __shared__ float ls[128];

    const int v = tok[b];
    const float2 e = ((const float2*)(emb + (size_t)v * E))[t];
    qs[2 * t] = e.x; qs[2 * t + 1] = e.y;
    ushort2 eb; eb.x = f2b(e.x); eb.y = f2b(e.y);
    *(ushort2*)&c2b[(size_t)b * 1024 + 2 * t] = eb;
    const float2 h = ((const float2*)(hidden0 + (size_t)b * H))[t];
    qs[512 + 2 * t] = h.x; qs[512 + 2 * t + 1] = h.y;
    __syncthreads();

    float s = -1e30f;
    if (t < MAXLEN) {
        const float4* w4 = (const float4*)(attn_W + (size_t)t * 1024);
        const float4* q4 = (const float4*)qs;
        float ax = 0.f, ay = 0.f, az = 0.f, aw = 0.f;
        #pragma unroll 8
        for (int k = 0; k < 256; ++k) {
            const float4 a = q4[k], w = w4[k];
            ax += a.x * w.x; ay += a.y * w.y; az += a.z * w.z; aw += a.w * w.w;
        }
        s = (ax + ay) + (az + aw) + attn_b[t];
    }
    if (t < 128) ls[t] = s;
    __syncthreads();

    float mx = -1e30f;
    for (int i = 0; i < 128; ++i) mx = fmaxf(mx, ls[i]);
    __syncthreads();

    float ex = 0.f;
    if (t < MAXLEN) ex = expf(s - mx);
    if (t < 128) ls[t] = ex;
    __syncthreads();

    float sum = 0.f;
    for (int i = 0; i < 128; ++i) sum += ls[i];
    const float inv = 1.0f / sum;

    if (t < MAXLEN) attnw[(size_t)b * MAXLEN + t] = ex * inv;

    float accx = 0.f, accy = 0.f;
    const float2* encb = (const float2*)(enc + (size_t)b * MAXLEN * H);
    for (int l = 0; l < MAXLEN; ++l) {
        const float wl = ls[l];
        const float2 ev = encb[(size_t)l * 256 + t];
        accx += wl * ev.x; accy += wl * ev.y;
    }
    ushort2 ab; ab.x = f2b(accx * inv); ab.y = f2b(accy * inv);
    *(ushort2*)&c2b[(size_t)b * 1024 + 512 + 2 * t] = ab;
}

// ---------------------------------------------------------------------------
// batched fp32 -> bf16 conversion over up to 5 segments; 2048 elems/block
// e0..e3 are exclusive prefix block counts; segment 4 takes the rest.
// ---------------------------------------------------------------------------
__global__ __launch_bounds__(256) void batch_f2b_kernel(
    const float* __restrict__ s0, unsigned short* __restrict__ d0, int e0,
    const float* __restrict__ s1, unsigned short* __restrict__ d1, int e1,
    const float* __restrict__ s2, unsigned short* __restrict__ d2, int e2,
    const float* __restrict__ s3, unsigned short* __restrict__ d3, int e3,
    const float* __restrict__ s4, unsigned short* __restrict__ d4)
{
    int blk = blockIdx.x;
    const float* s; unsigned short* d;
    if      (blk < e0) { s = s0; d = d0; }
    else if (blk < e1) { s = s1; d = d1; blk -= e0; }
    else if (blk < e2) { s = s2; d = d2; blk -= e1; }
    else if (blk < e3) { s = s3; d = d3; blk -= e2; }
    else               { s = s4; d = d4; blk -= e3; }
    const size_t i = ((size_t)blk * 256 + threadIdx.x) * 8;
    const float4 a = *(const float4*)(s + i);
    const float4 b = *(const float4*)(s + i + 4);
    ushort8 o;
    o[0] = f2b(a.x); o[1] = f2b(a.y); o[2] = f2b(a.z); o[3] = f2b(a.w);
    o[4] = f2b(b.x); o[5] = f2b(b.y); o[6] = f2b(b.z); o[7] = f2b(b.w);
    *(ushort8*)(d + i) = o;
}

// ---------------------------------------------------------------------------
// bf16 MFMA NT GEMM core: C[m,n] = A[m,:] . W[n,:] + bias[n]
// BM=BN=128, BK=32, 256 thr (4 waves, 2x2 of 64x64), m97-class structure.
// OUTBF=1: LDS-staged dense bf16 epilogue (full-sector ushort8 stores).
// PARTIALS: per-(row, 128-col tile) softmax partials (max, sum-exp).
// Must have exactly ONE call site per kernel (static __shared__ inside).
// ---------------------------------------------------------------------------
template<int RELU, int OUTBF, int PARTIALS>
__device__ __forceinline__ void gemm_core(
    const unsigned short* __restrict__ A, const unsigned short* __restrict__ Wb,
    const float* __restrict__ bias, void* __restrict__ Cv,
    int M, int N, int K, int ldc, int colOff,
    float* __restrict__ pmax_g, float* __restrict__ psum_g, int bm, int bn)
{
    __shared__ __align__(16) unsigned short As[2][4096];
    __shared__ __align__(16) unsigned short Bs[2][4096];

    const int tid  = threadIdx.x;
    const int lane = tid & 63;
    const int wid  = tid >> 6;
    const int wr   = (wid >> 1) * 64;
    const int wc   = (wid & 1) * 64;
    const int fr   = lane & 15;
    const int fk   = (lane >> 4) * 8;

    f32x4 acc[4][4];
    #pragma unroll
    for (int m = 0; m < 4; ++m)
        #pragma unroll
        for (int n = 0; n < 4; ++n) acc[m][n] = (f32x4)0.f;

    const int srow = tid >> 2;
    const int sk   = (tid & 3) * 8;

    const unsigned short* ga = A  + (size_t)(bm + srow) * K + sk;
    const unsigned short* gb = Wb + (size_t)(bn + srow) * K + sk;

    {
        GLOAD16(ga,                    &As[0][tid * 8]);
        GLOAD16(ga + (size_t)64 * K,   &As[0][2048 + tid * 8]);
        GLOAD16(gb,                    &Bs[0][tid * 8]);
        GLOAD16(gb + (size_t)64 * K,   &Bs[0][2048 + tid * 8]);
    }

    int buf = 0;
    for (int k0 = 0; k0 < K; k0 += 32) {
        __syncthreads();

        if (k0 + 32 < K) {
            const int nb = buf ^ 1;
            GLOAD16(ga + k0 + 32,                  &As[nb][tid * 8]);
            GLOAD16(ga + k0 + 32 + (size_t)64 * K, &As[nb][2048 + tid * 8]);
            GLOAD16(gb + k0 + 32,                  &Bs[nb][tid * 8]);
            GLOAD16(gb + k0 + 32 + (size_t)64 * K, &Bs[nb][2048 + tid * 8]);
        }

        bf16x8 af[4], bf_[4];
        #pragma unroll
        for (int m = 0; m < 4; ++m)
            af[m] = *(const bf16x8*)&As[buf][(wr + m * 16 + fr) * 32 + fk];
        #pragma unroll
        for (int n = 0; n < 4; ++n)
            bf_[n] = *(const bf16x8*)&Bs[buf][(wc + n * 16 + fr) * 32 + fk];

        #pragma unroll
        for (int m = 0; m < 4; ++m)
            #pragma unroll
            for (int n = 0; n < 4; ++n)
                acc[m][n] = __builtin_amdgcn_mfma_f32_16x16x32_bf16(
                    af[m], bf_[n], acc[m][n], 0, 0, 0);

        buf ^= 1;
    }

    float bv[4];
    #pragma unroll
    for (int n = 0; n < 4; ++n) bv[n] = bias[bn + wc + n * 16 + fr];

    if constexpr (PARTIALS) {
        __shared__ float pm_s[2][2][64];
        __shared__ float ps_s[2][2][64];
        const int wrIdx = wid >> 1, wcIdx = wid & 1;

        #pragma unroll
        for (int m = 0; m < 4; ++m) {
            #pragma unroll
            for (int r = 0; r < 4; ++r) {
                float vmax = -1e30f;
                #pragma unroll
                for (int n = 0; n < 4; ++n) vmax = fmaxf(vmax, acc[m][n][r] + bv[n]);
                vmax = fmaxf(vmax, __shfl_xor(vmax, 1));
                vmax = fmaxf(vmax, __shfl_xor(vmax, 2));
                vmax = fmaxf(vmax, __shfl_xor(vmax, 4));
                vmax = fmaxf(vmax, __shfl_xor(vmax, 8));
                float vsum = 0.f;
                #pragma unroll
                for (int n = 0; n < 4; ++n) vsum += expf(acc[m][n][r] + bv[n] - vmax);
                vsum += __shfl_xor(vsum, 1);
                vsum += __shfl_xor(vsum, 2);
                vsum += __shfl_xor(vsum, 4);
                vsum += __shfl_xor(vsum, 8);
                const int rowh = m * 16 + (lane >> 4) * 4 + r;
                if (fr == 0) { pm_s[wrIdx][wcIdx][rowh] = vmax; ps_s[wrIdx][wcIdx][rowh] = vsum; }
            }
        }
        __syncthreads();
        if (wcIdx == 0) {
            const float m0 = pm_s[wrIdx][0][lane], m1 = pm_s[wrIdx][1][lane];
            const float s0 = ps_s[wrIdx][0][lane], s1 = ps_s[wrIdx][1][lane];
            const float Mx = fmaxf(m0, m1);
            const float S  = s0 * expf(m0 - Mx) + s1 * expf(m1 - Mx);
            const int row = bm + wr + lane;
            const int nt  = bn >> 7;
            const int NT  = N >> 7;
            pmax_g[(size_t)row * NT + nt] = Mx;
            psum_g[(size_t)row * NT + nt] = S;
        }
    }

    if constexpr (OUTBF) {
        __syncthreads();
        unsigned short* smb = (wr == 0) ? (unsigned short*)As : (unsigned short*)Bs;
        #pragma unroll
        for (int m = 0; m < 4; ++m) {
            #pragma unroll
            for (int n = 0; n < 4; ++n) {
                #pragma unroll
                for (int r = 0; r < 4; ++r) {
                    float v = acc[m][n][r] + bv[n];
                    if (RELU) v = fmaxf(v, 0.f);
                    const int row  = m * 16 + (lane >> 4) * 4 + r;
                    const int col  = wc + n * 16 + fr;
                    const int cc   = col ^ ((row & 12) << 3);
                    smb[row * 128 + cc] = f2b(v);
                }
            }
        }
        __syncthreads();
        unsigned short* Cb = (unsigned short*)Cv;
        const int rrow = tid >> 4;
        const int cch  = (tid & 15) * 8;
        #pragma unroll
        for (int p = 0; p < 8; ++p) {
            const int row  = p * 16 + rrow;
            const int lrow = row & 63;
            unsigned short* smr = (p < 4) ? (unsigned short*)As : (unsigned short*)Bs;
            const int cc = cch ^ ((row & 12) << 3);
            const ushort8 v = *(const ushort8*)&smr[lrow * 128 + cc];
            *(ushort8*)&Cb[(size_t)(bm + row) * ldc + colOff + bn + cch] = v;
        }
    } else {
        float* Cf = (float*)Cv;
        #pragma unroll
        for (int m = 0; m < 4; ++m) {
            #pragma unroll
            for (int n = 0; n < 4; ++n) {
                const int col = bn + wc + n * 16 + fr;
                const int row = bm + wr + m * 16 + (lane >> 4) * 4;
                #pragma unroll
                for (int r = 0; r < 4; ++r) {
                    float v = acc[m][n][r] + bv[n];
                    if (RELU) v = fmaxf(v, 0.f);
                    Cf[(size_t)(row + r) * ldc + colOff + col] = v;
                }
            }
        }
    }
}

template<int RELU, int OUTBF, int PARTIALS, int GSWAP>
__global__ __launch_bounds__(256) void gemm_bf16_nt(
    const unsigned short* __restrict__ A, const unsigned short* __restrict__ Wb,
    const float* __restrict__ bias, void* __restrict__ Cv,
    int M, int N, int K, int ldc, int colOff,
    float* __restrict__ pmax_g, float* __restrict__ psum_g)
{
    const int bn = (GSWAP ? blockIdx.y : blockIdx.x) * 128;
    const int bm = (GSWAP ? blockIdx.x : blockIdx.y) * 128;
    gemm_core<RELU, OUTBF, PARTIALS>(A, Wb, bias, Cv, M, N, K, ldc, colOff,
                                     pmax_g, psum_g, bm, bn);
}

// two independent GEMMs (same M,N,K) in one launch; blockIdx.z selects.
__global__ __launch_bounds__(256) void gemm_bf16_dual(
    const unsigned short* __restrict__ A0, const unsigned short* __restrict__ W0,
    const float* __restrict__ b0, void* __restrict__ C0,
    const unsigned short* __restrict__ A1, const unsigned short* __restrict__ W1,
    const float* __restrict__ b1, void* __restrict__ C1,
    int M, int N, int K, int ldc)
{
    const int bn = blockIdx.x * 128;
    const int bm = blockIdx.y * 128;
    const unsigned short* A = blockIdx.z ? A1 : A0;
    const unsigned short* W = blockIdx.z ? W1 : W0;
    const float* bias       = blockIdx.z ? b1 : b0;
    void* C                 = blockIdx.z ? C1 : C0;
    gemm_core<0, 1, 0>(A, W, bias, C, M, N, K, ldc, 0, nullptr, nullptr, bm, bn);
}

// ---------------------------------------------------------------------------
// fp32 NT GEMM (fallback for logits if ws too small)
// ---------------------------------------------------------------------------
template<int RELU>
__global__ __launch_bounds__(256) void gemm_nt(
    const float* __restrict__ A, const float* __restrict__ W,
    const float* __restrict__ bias, float* __restrict__ C,
    int M, int N, int K)
{
    constexpr int BM = 128, BN = 128, BK = 32;
    __shared__ float As[BK][BM + 4];
    __shared__ float Bs[BK][BN + 4];

    const int tid = threadIdx.x;
    const int bn = blockIdx.x * BN;
    const int bm = blockIdx.y * BM;
    const int tx = tid & 15;
    const int ty = tid >> 4;

    float acc[8][8];
    #pragma unroll
    for (int i = 0; i < 8; ++i)
        #pragma unroll
        for (int j = 0; j < 8; ++j) acc[i][j] = 0.f;

    const int lkv = tid & 7;
    const int lm0 = tid >> 3;

    for (int k0 = 0; k0 < K; k0 += BK) {
        #pragma unroll
        for (int r = 0; r < 4; ++r) {
            const int m = lm0 + 32 * r;
            const float4 va = *(const float4*)(A + (size_t)(bm + m) * K + k0 + lkv * 4);
            As[lkv * 4 + 0][m] = va.x; As[lkv * 4 + 1][m] = va.y;
            As[lkv * 4 + 2][m] = va.z; As[lkv * 4 + 3][m] = va.w;
            const float4 vb = *(const float4*)(W + (size_t)(bn + m) * K + k0 + lkv * 4);
            Bs[lkv * 4 + 0][m] = vb.x; Bs[lkv * 4 + 1][m] = vb.y;
            Bs[lkv * 4 + 2][m] = vb.z; Bs[lkv * 4 + 3][m] = vb.w;
        }
        __syncthreads();

        #pragma unroll
        for (int kk = 0; kk < BK; ++kk) {
            float a[8], bb[8];
            *(float4*)&a[0]  = *(const float4*)&As[kk][ty * 8];
            *(float4*)&a[4]  = *(const float4*)&As[kk][ty * 8 + 4];
            *(float4*)&bb[0] = *(const float4*)&Bs[kk][tx * 8];
            *(float4*)&bb[4] = *(const float4*)&Bs[kk][tx * 8 + 4];
            #pragma unroll
            for (int i = 0; i < 8; ++i)
                #pragma unroll
                for (int j = 0; j < 8; ++j) acc[i][j] += a[i] * bb[j];
        }
        __syncthreads();
    }

    #pragma unroll
    for (int i = 0; i < 8; ++i) {
        const int row = bm + ty * 8 + i;
        float* crow = C + (size_t)row * N + bn + tx * 8;
        #pragma unroll
        for (int j = 0; j < 8; ++j) {
            float v = acc[i][j] + bias[bn + tx * 8 + j];
            if (RELU) v = fmaxf(v, 0.f);
            crow[j] = v;
        }
    }
}

// ---------------------------------------------------------------------------
// GRU gates (vectorized x8): hnew = (1-z)*n + z*h  (fp32 + bf16 outputs)
// ---------------------------------------------------------------------------
__global__ __launch_bounds__(256) void gru_gates_kernel(
    const unsigned short* __restrict__ gi, const unsigned short* __restrict__ gh,
    const float* __restrict__ h, float* __restrict__ hnew,
    unsigned short* __restrict__ hnew_b)
{
    const int idx = blockIdx.x * 256 + threadIdx.x;     // over B*H/8
    const int b  = idx >> 6;
    const int j8 = (idx & 63) * 8;
    const size_t base = (size_t)b * 1536;
    const ushort8 vir = *(const ushort8*)&gi[base + j8];
    const ushort8 viz = *(const ushort8*)&gi[base + 512 + j8];
    const ushort8 vin = *(const ushort8*)&gi[base + 1024 + j8];
    const ushort8 vhr = *(const ushort8*)&gh[base + j8];
    const ushort8 vhz = *(const ushort8*)&gh[base + 512 + j8];
    const ushort8 vhn = *(const ushort8*)&gh[base + 1024 + j8];
    const size_t hi = (size_t)b * 512 + j8;
    const float4 h0 = *(const float4*)&h[hi];
    const float4 h1 = *(const float4*)&h[hi + 4];
    const float hval[8] = {h0.x, h0.y, h0.z, h0.w, h1.x, h1.y, h1.z, h1.w};
    float hv[8];
    ushort8 ob;
    #pragma unroll
    for (int k = 0; k < 8; ++k) {
        const float r = 1.f / (1.f + expf(-(b2f(vir[k]) + b2f(vhr[k]))));
        const float z = 1.f / (1.f + expf(-(b2f(viz[k]) + b2f(vhz[k]))));
        const float n = tanhf(b2f(vin[k]) + r * b2f(vhn[k]));
        hv[k] = (1.f - z) * n + z * hval[k];
        ob[k] = f2b(hv[k]);
    }
    float4 o0, o1;
    o0.x = hv[0]; o0.y = hv[1]; o0.z = hv[2]; o0.w = hv[3];
    o1.x = hv[4]; o1.y = hv[5]; o1.z = hv[6]; o1.w = hv[7];
    *(float4*)&hnew[hi]     = o0;
    *(float4*)&hnew[hi + 4] = o1;
    *(ushort8*)&hnew_b[hi]  = ob;
}

// ---------------------------------------------------------------------------
// merge per-tile softmax partials into per-row (max, 1/sum); 1 wave per row
// ---------------------------------------------------------------------------
__global__ __launch_bounds__(64) void softmax_rowstats_kernel(
    const float* __restrict__ pmax, const float* __restrict__ psum,
    float* __restrict__ rowM, float* __restrict__ rowInvS, int NT)
{
    const int row = blockIdx.x, t = threadIdx.x;
    float Mx = -1e30f, S = 0.f;
    for (int i = t; i < NT; i += 64) {
        const float m = pmax[(size_t)row * NT + i];
        const float s = psum[(size_t)row * NT + i];
        const float nm = fmaxf(Mx, m);
        S = S * expf(Mx - nm) + s * expf(m - nm);
        Mx = nm;
    }
    #pragma unroll
    for (int mask = 1; mask < 64; mask <<= 1) {
        const float m2 = __shfl_xor(Mx, mask);
        const float s2 = __shfl_xor(S, mask);
        const float nm = fmaxf(Mx, m2);
        S = S * expf(Mx - nm) + s2 * expf(m2 - nm);
        Mx = nm;
    }
    if (t == 0) { rowM[row] = Mx; rowInvS[row] = 1.f / S; }
}

// ---------------------------------------------------------------------------
// apply from bf16 logits packed in the TOP half of each fp32 row slot.
// Register-staged: all reads before any write within the block.
// ---------------------------------------------------------------------------
__global__ __launch_bounds__(256) void softmax_apply_tophalf_kernel(
    float* logits, const float* __restrict__ rowM,
    const float* __restrict__ rowInvS)
{
    const int row = blockIdx.x, t = threadIdx.x;
    const float Mx = rowM[row], is = rowInvS[row];
    const unsigned short* src = (const unsigned short*)logits + (size_t)row * (2 * V) + V;
    ushort8 buf[16];
    #pragma unroll
    for (int k = 0; k < 16; ++k) {
        const int i = t + 256 * k;
        if (i < V / 8) buf[k] = *(const ushort8*)&src[i * 8];
    }
    __syncthreads();
    float* dst = logits + (size_t)row * V;
    #pragma unroll
    for (int k = 0; k < 16; ++k) {
        const int i = t + 256 * k;
        if (i < V / 8) {
            float4 o0, o1;
            o0.x = expf(b2f(buf[k][0]) - Mx) * is;
            o0.y = expf(b2f(buf[k][1]) - Mx) * is;
            o0.z = expf(b2f(buf[k][2]) - Mx) * is;
            o0.w = expf(b2f(buf[k][3]) - Mx) * is;
            o1.x = expf(b2f(buf[k][4]) - Mx) * is;
            o1.y = expf(b2f(buf[k][5]) - Mx) * is;
            o1.z = expf(b2f(buf[k][6]) - Mx) * is;
            o1.w = expf(b2f(buf[k][7]) - Mx) * is;
            *(float4*)&dst[i * 8]     = o0;
            *(float4*)&dst[i * 8 + 4] = o1;
        }
    }
}

// ---------------------------------------------------------------------------
// in-place row softmax (fallback)
// ---------------------------------------------------------------------------
__global__ __launch_bounds__(256) void softmax_rows_kernel(float* __restrict__ logits, int N)
{
    const int b = blockIdx.x, t = threadIdx.x;
    __shared__ float red[256];
    float* row = logits + (size_t)b * N;

    float mx = -1e30f;
    for (int i = t; i < N; i += 256) mx = fmaxf(mx, row[i]);
    red[t] = mx; __syncthreads();
    for (int s = 128; s > 0; s >>= 1) { if (t < s) red[t] = fmaxf(red[t], red[t + s]); __syncthreads(); }
    mx = red[0]; __syncthreads();

    float sum = 0.f;
    for (int i = t; i < N; i += 256) sum += expf(row[i] - mx);
    red[t] = sum; __syncthreads();
    for (int s = 128; s > 0; s >>= 1) { if (t < s) red[t] += red[t + s]; __syncthreads(); }
    const float inv = 1.0f / red[0];
    __syncthreads();

    for (int i = t; i < N; i += 256) row[i] = expf(row[i] - mx) * inv;
}

// ---------------------------------------------------------------------------
extern "C" void kernel_launch(void* const* d_in, const int* in_sizes, int n_in,
                              void* d_out, int out_size, void* d_ws, size_t ws_size,
                              hipStream_t stream)
{
    const int*   tok    = (const int*)d_in[0];
    const float* hidden = (const float*)d_in[1];
    const float* enc    = (const float*)d_in[2];
    const float* emb    = (const float*)d_in[3];
    const float* attn_W = (const float*)d_in[4];
    const float* attn_b = (const float*)d_in[5];
    const float* comb_W = (const float*)d_in[6];
    const float* comb_b = (const float*)d_in[7];
    const float* W_ih   = (const float*)d_in[8];
    const float* W_hh   = (const float*)d_in[9];
    const float* b_ih   = (const float*)d_in[10];
    const float* b_hh   = (const float*)d_in[11];
    const float* out_W  = (const float*)d_in[12];
    const float* out_b  = (const float*)d_in[13];

    float* out   = (float*)d_out;
    float* pred  = out;                             // B*V
    float* hid_o = out + (size_t)B * V;             // NL*B*H
    float* attnw = hid_o + (size_t)NL * B * H;      // B*MAXLEN

    // bf16 scratch carved from pred region (dead until the logits GEMM)
    unsigned short* c2b    = (unsigned short*)pred;         // B*1024
    unsigned short* xb     = c2b  + (size_t)B * 1024;       // B*512
    unsigned short* h01b   = xb   + (size_t)B * 512;        // NL*B*512
    unsigned short* hn0b   = h01b + (size_t)NL * B * 512;   // B*512
    unsigned short* gi_b   = hn0b + (size_t)B * 512;        // B*1536
    unsigned short* gh_b   = gi_b + (size_t)B * 1536;       // B*1536
    unsigned short* Wihb   = gh_b + (size_t)B * 1536;       // 2*1536*512
    unsigned short* Whhb   = Wihb + (size_t)NL * 1536 * 512;
    unsigned short* combWb = Whhb + (size_t)NL * 1536 * 512; // 512*1024
    unsigned short* hn1b_fallback = combWb + (size_t)512 * 1024;

    // final-GEMM inputs + softmax partials live in d_ws
    const size_t outWb_e = (size_t)V * H;
    const size_t hn1b_e  = (size_t)B * H;
    const int    NT      = V / 128;                 // 250
    const size_t bf_bytes = (outWb_e + hn1b_e) * sizeof(unsigned short);
    const size_t pt_bytes = ((size_t)B * NT * 2 + 2 * B) * sizeof(float);
    const bool lvl1 = ws_size >= bf_bytes;
    const bool lvl2 = ws_size >= bf_bytes + pt_bytes;

    unsigned short* outWb = (unsigned short*)d_ws;
    unsigned short* hn1b  = lvl1 ? outWb + outWb_e : hn1b_fallback;
    float* pmax_g  = (float*)((char*)d_ws + bf_bytes);
    float* psum_g  = pmax_g + (size_t)B * NT;
    float* rowM    = psum_g + (size_t)B * NT;
    float* rowInvS = rowM + B;

    unsigned short* h0b = h01b;
    unsigned short* h1b = h01b + (size_t)B * 512;

    // 1. fused embed + attention (writes attnw fp32, c2b bf16)
    embed_attn_kernel<<<B, 256, 0, stream>>>(
        tok, emb, hidden, attn_W, attn_b, enc, attnw, c2b);

    // 2. batched conversions: comb_W(256) W_ih(768) W_hh(768) hidden(2048) [out_W(8000)]
    {
        const int e0 = 256, e1 = e0 + 768, e2 = e1 + 768, e3 = e2 + 2048;
        const int nblk = lvl1 ? e3 + 8000 : e3;
        batch_f2b_kernel<<<nblk, 256, 0, stream>>>(
            comb_W, combWb, e0,
            W_ih,   Wihb,   e1,
            W_hh,   Whhb,   e2,
            hidden, h01b,   e3,
            out_W,  outWb);
    }

    // 3. x = relu(c2 @ combine_W.T + b)   [4096 x 512 x 1024] -> bf16 dense
    gemm_bf16_nt<1, 1, 0, 0><<<dim3(512 / 128, B / 128), 256, 0, stream>>>(
        c2b, combWb, comb_b, xb, B, 512, 1024, 512, 0, nullptr, nullptr);

    // 4. GRU layer 0: gi & gh in one launch
    gemm_bf16_dual<<<dim3(1536 / 128, B / 128, 2), 256, 0, stream>>>(
        xb,  Wihb, b_ih, gi_b,
        h0b, Whhb, b_hh, gh_b, B, 1536, 512, 1536);
    gru_gates_kernel<<<(B * H / 8) / 256, 256, 0, stream>>>(
        gi_b, gh_b, hidden, hid_o, hn0b);

    // 5. GRU layer 1
    gemm_bf16_dual<<<dim3(1536 / 128, B / 128, 2), 256, 0, stream>>>(
        hn0b, Wihb + (size_t)1536 * 512, b_ih + 1536, gi_b,
        h1b,  Whhb + (size_t)1536 * 512, b_hh + 1536, gh_b, B, 1536, 512, 1536);
    gru_gates_kernel<<<(B * H / 8) / 256, 256, 0, stream>>>(
        gi_b, gh_b, hidden + (size_t)B * H, hid_o + (size_t)B * H, hn1b);

    // 6. logits + softmax
    if (lvl2) {
        gemm_bf16_nt<0, 1, 1, 1><<<dim3(B / 128, V / 128), 256, 0, stream>>>(
            hn1b, outWb, out_b, pred, B, V, 512, 2 * V, V, pmax_g, psum_g);
        softmax_rowstats_kernel<<<B, 64, 0, stream>>>(pmax_g, psum_g, rowM, rowInvS, NT);
        softmax_apply_tophalf_kernel<<<B, 256, 0, stream>>>(pred, rowM, rowInvS);
    } else if (lvl1) {
        gemm_bf16_nt<0, 0, 0, 1><<<dim3(B / 128, V / 128), 256, 0, stream>>>(
            hn1b, outWb, out_b, pred, B, V, 512, V, 0, nullptr, nullptr);
        softmax_rows_kernel<<<B, 256, 0, stream>>>(pred, V);
    } else {
        gemm_nt<0><<<dim3(V / 128, B / 128), 256, 0, stream>>>(
            hid_o + (size_t)B * H, out_W, out_b, pred, B, V, 512);
        softmax_rows_kernel<<<B, 256, 0, stream>>>(pred, V);
    }
}